// Round 3
// baseline (253.522 us; speedup 1.0000x reference)
//
#include <hip/hip_runtime.h>

#define NN 100
#define CC 32
#define HEE 32
#define FF 64
#define TILE 10
#define PTP 102  // padded PT row length (stride%32=6 -> conflict-free b64/b32)

// ---------------- K1: hi = x@ew1[:C]+eb1, hj = x@ew1[C:], d0 ----------------
__global__ __launch_bounds__(64) void k_hidden(
    const float* __restrict__ x, const float* __restrict__ A,
    const float* __restrict__ ew1, const float* __restrict__ eb1,
    float* __restrict__ hi, float* __restrict__ hj, float* __restrict__ d0) {
  int bn = blockIdx.x;
  int t = threadIdx.x;
  __shared__ float xr[CC];
  if (t < CC) xr[t] = x[bn * CC + t];

  const float* arow = A + (size_t)bn * NN;
  float s = 0.f;
  for (int j = t; j < NN; j += 64) s += arow[j];
#pragma unroll
  for (int off = 32; off > 0; off >>= 1) s += __shfl_down(s, off);
  if (t == 0) d0[bn] = 1.0f / sqrtf(s + 1.0f + 1e-5f);

  __syncthreads();
  int k = t & 31;
  const float* w = ew1 + (t < 32 ? 0 : CC * HEE) + k;
  float acc = (t < 32) ? eb1[k] : 0.f;
#pragma unroll
  for (int c = 0; c < CC; ++c) acc += xr[c] * w[c * HEE];
  if (t < 32) hi[bn * HEE + k] = acc;
  else        hj[bn * HEE + k] = acc;
}

// ---------------- K2: Ahat1 = A_pred + I, d1 ----------------
__global__ __launch_bounds__(256) void k_edge(
    const float* __restrict__ hi, const float* __restrict__ hj,
    const float* __restrict__ ew2, const float* __restrict__ eb2,
    const float* __restrict__ mask,
    float* __restrict__ Ahat1, float* __restrict__ d1) {
  __shared__ __align__(16) float shi[NN * HEE];
  __shared__ __align__(16) float shj[NN * HEE];
  __shared__ __align__(16) float sw2[HEE];
  __shared__ float sm[NN];
  __shared__ float sA[TILE][NN];
  int t = threadIdx.x;
  int b = blockIdx.x / 10;
  int i0 = (blockIdx.x % 10) * TILE;

  const float4* hi4 = (const float4*)(hi + (size_t)b * NN * HEE);
  const float4* hj4 = (const float4*)(hj + (size_t)b * NN * HEE);
  float4* shi4 = (float4*)shi;
  float4* shj4 = (float4*)shj;
  for (int v = t; v < NN * 8; v += 256) {
    int j = v >> 3, k4 = v & 7;
    int sw = (j << 3) | (k4 ^ (j & 7));
    shi4[sw] = hi4[v];
    shj4[sw] = hj4[v];
  }
  if (t < HEE) sw2[t] = ew2[t];
  if (t < NN) sm[t] = mask[b * NN + t];
  __syncthreads();

  float e2 = eb2[0];
  float4* sw24 = (float4*)sw2;
  for (int p = t; p < TILE * NN; p += 256) {
    int r = p / NN, j = p % NN, i = i0 + r;
    float val;
    if (j == i) {
      val = 1.0f;
    } else {
      float a1 = 0.f, a2 = 0.f;
#pragma unroll
      for (int k4 = 0; k4 < 8; ++k4) {
        float4 hii = shi4[(i << 3) | (k4 ^ (i & 7))];
        float4 hji = shj4[(i << 3) | (k4 ^ (i & 7))];
        float4 hij = shi4[(j << 3) | (k4 ^ (j & 7))];
        float4 hjj = shj4[(j << 3) | (k4 ^ (j & 7))];
        float4 w4 = sw24[k4];
        a1 += fmaxf(hii.x + hjj.x, 0.f) * w4.x;
        a2 += fmaxf(hij.x + hji.x, 0.f) * w4.x;
        a1 += fmaxf(hii.y + hjj.y, 0.f) * w4.y;
        a2 += fmaxf(hij.y + hji.y, 0.f) * w4.y;
        a1 += fmaxf(hii.z + hjj.z, 0.f) * w4.z;
        a2 += fmaxf(hij.z + hji.z, 0.f) * w4.z;
        a1 += fmaxf(hii.w + hjj.w, 0.f) * w4.w;
        a2 += fmaxf(hij.w + hji.w, 0.f) * w4.w;
      }
      val = expf(0.5f * (a1 + a2) + e2) * sm[i] * sm[j];
    }
    sA[r][j] = val;
    Ahat1[((size_t)b * NN + i) * NN + j] = val;
  }
  __syncthreads();
  if (t < TILE) {
    float s = 0.f;
    for (int j = 0; j < NN; ++j) s += sA[t][j];
    d1[b * NN + i0 + t] = 1.0f / sqrtf(s + 1e-5f);
  }
}

// ---------------- K_pre: P0[b][rel][i][f] = sum_c x[b][i][c] * gw0[rel*32+c][f] ----------------
// grid 512 = b(127&) x q(>>7); wave handles rowgroup rg = wid*4+q (8 rows), lane = f.
__global__ __launch_bounds__(256, 2) void k_pre2(
    const float* __restrict__ x, const float* __restrict__ gw0,
    float* __restrict__ P) {
  int t = threadIdx.x;
  int b = blockIdx.x & 127;
  int q = blockIdx.x >> 7;
  int wid = __builtin_amdgcn_readfirstlane(t >> 6);
  int lane = t & 63;
  int rg = wid * 4 + q;
  int row0 = rg * 8;
  if (row0 >= NN) return;

  // preload W columns: wv[rel][c] = gw0[(rel*32+c)*64 + lane]
  float wv0[CC], wv1[CC];
#pragma unroll
  for (int c = 0; c < CC; ++c) {
    wv0[c] = gw0[(size_t)c * 64 + lane];
    wv1[c] = gw0[(size_t)(CC + c) * 64 + lane];
  }
  int rowc[8];
#pragma unroll
  for (int r = 0; r < 8; ++r) rowc[r] = min(row0 + r, NN - 1);

  float acc0[8], acc1[8];
#pragma unroll
  for (int r = 0; r < 8; ++r) { acc0[r] = 0.f; acc1[r] = 0.f; }

#pragma unroll
  for (int c4 = 0; c4 < CC / 4; ++c4) {
#pragma unroll
    for (int r = 0; r < 8; ++r) {
      float4 a4 = *(const float4*)(x + ((size_t)b * NN + rowc[r]) * CC + c4 * 4);
      int c = c4 * 4;
      acc0[r] += a4.x * wv0[c] + a4.y * wv0[c + 1] + a4.z * wv0[c + 2] + a4.w * wv0[c + 3];
      acc1[r] += a4.x * wv1[c] + a4.y * wv1[c + 1] + a4.z * wv1[c + 2] + a4.w * wv1[c + 3];
    }
  }
#pragma unroll
  for (int r = 0; r < 8; ++r) {
    int row = row0 + r;
    if (row < NN) {
      P[(((size_t)b * 2 + 0) * NN + row) * 64 + lane] = acc0[r];
      P[(((size_t)b * 2 + 1) * NN + row) * 64 + lane] = acc1[r];
    }
  }
}

// ---------------- K_layer ----------------
// out[i][f] = relu((d0_i*(sum_j A_ij*Pd0[j][f] + Pd0[i][f]) + d1_i*sum_j Ah1_ij*Pd1[j][f] + b[f])*m_i)
// where Pd_rel[j][f] = d_rel[j] * P[b][rel][j][f]  (staged transposed in LDS).
// Non-LAST: P_next[b][rel][i][f] = sum_k out[i][k] * Wn[rel*64+k][f]   (in-wave fused)
// LAST: pooled[b][rg][f] = max over wave's rows.
template <int LAST>
__global__ __launch_bounds__(256, 2) void k_layer(
    const float* __restrict__ A, const float* __restrict__ Ah1,
    const float* __restrict__ d0, const float* __restrict__ d1,
    const float* __restrict__ mask, const float* __restrict__ Pin,
    const float* __restrict__ bias, const float* __restrict__ Wn,
    float* __restrict__ Pout) {
  __shared__ __align__(16) float PT[2 * 64 * PTP];  // [rel][f][j] scaled by d[j]
  __shared__ __align__(16) float srow[4][8][64];
  int t = threadIdx.x;
  int b = blockIdx.x & 127;
  int q = blockIdx.x >> 7;

  // stage PT[rel][f][j] = P[b][rel][j][f] * d_rel[j]
  {
    const float4* P4 = (const float4*)(Pin + (size_t)b * 12800);
    const float* d0b = d0 + b * NN;
    const float* d1b = d1 + b * NN;
    for (int v = t; v < 3200; v += 256) {
      int rel = (v >= 1600) ? 1 : 0;
      int rem = v - rel * 1600;
      int j = rem >> 4, f4 = rem & 15;
      float4 p = P4[v];
      float dv = rel ? d1b[j] : d0b[j];
      float* dst = PT + rel * 64 * PTP + (f4 * 4) * PTP + j;
      dst[0 * PTP] = p.x * dv;
      dst[1 * PTP] = p.y * dv;
      dst[2 * PTP] = p.z * dv;
      dst[3 * PTP] = p.w * dv;
    }
  }
  __syncthreads();

  int wid = __builtin_amdgcn_readfirstlane(t >> 6);
  int lane = t & 63;
  int rg = wid * 4 + q;
  int row0 = rg * 8;
  if (row0 >= NN) return;

  int rowc[8];
#pragma unroll
  for (int r = 0; r < 8; ++r) rowc[r] = min(row0 + r, NN - 1);

  float acc0[8], acc1[8];
#pragma unroll
  for (int r = 0; r < 8; ++r) { acc0[r] = 0.f; acc1[r] = 0.f; }

  // rel0: stream raw A rows via s_load, Pd0 via conflict-free ds_read_b64
  {
    const float2* pt2 = (const float2*)(PT + (size_t)lane * PTP);
    for (int j4 = 0; j4 < NN / 4; ++j4) {
      float2 pa = pt2[j4 * 2];
      float2 pb = pt2[j4 * 2 + 1];
#pragma unroll
      for (int r = 0; r < 8; ++r) {
        float4 a4 = *(const float4*)(A + ((size_t)b * NN + rowc[r]) * NN + j4 * 4);
        acc0[r] += a4.x * pa.x + a4.y * pa.y + a4.z * pb.x + a4.w * pb.y;
      }
    }
  }
  // rel1: Ah1 (already includes +I)
  {
    const float2* pt2 = (const float2*)(PT + 64 * PTP + (size_t)lane * PTP);
    for (int j4 = 0; j4 < NN / 4; ++j4) {
      float2 pa = pt2[j4 * 2];
      float2 pb = pt2[j4 * 2 + 1];
#pragma unroll
      for (int r = 0; r < 8; ++r) {
        float4 a4 = *(const float4*)(Ah1 + ((size_t)b * NN + rowc[r]) * NN + j4 * 4);
        acc1[r] += a4.x * pa.x + a4.y * pa.y + a4.z * pb.x + a4.w * pb.y;
      }
    }
  }

  float vb = bias[lane];
  float outv[8];
#pragma unroll
  for (int r = 0; r < 8; ++r) {
    float d0r = d0[b * NN + rowc[r]];
    float d1r = d1[b * NN + rowc[r]];
    float mr = mask[b * NN + rowc[r]];
    float pdiag = PT[(size_t)lane * PTP + rowc[r]];  // Pd0[rowc][lane] (+I correction)
    float v = (acc0[r] + pdiag) * d0r + acc1[r] * d1r;
    v = (v + vb) * mr;
    outv[r] = fmaxf(v, 0.f);
  }

  if (LAST) {
    float mx = outv[0];
#pragma unroll
    for (int r = 1; r < 8; ++r) mx = fmaxf(mx, outv[r]);
    Pout[((size_t)b * 16 + rg) * 64 + lane] = mx;
    return;
  }

  // phase 2: P_next = out @ Wn (in-wave; srow is wave-private, no barrier needed)
#pragma unroll
  for (int r = 0; r < 8; ++r) srow[wid][r][lane] = outv[r];

  float wv0[64], wv1[64];
#pragma unroll
  for (int k = 0; k < 64; ++k) {
    wv0[k] = Wn[(size_t)k * 64 + lane];
    wv1[k] = Wn[(size_t)(64 + k) * 64 + lane];
  }
  float pacc0[8], pacc1[8];
#pragma unroll
  for (int r = 0; r < 8; ++r) { pacc0[r] = 0.f; pacc1[r] = 0.f; }

  for (int k4 = 0; k4 < 16; ++k4) {
#pragma unroll
    for (int r = 0; r < 8; ++r) {
      float4 s4 = *(const float4*)&srow[wid][r][k4 * 4];  // broadcast read
      int k = k4 * 4;
      pacc0[r] += s4.x * wv0[k] + s4.y * wv0[k + 1] + s4.z * wv0[k + 2] + s4.w * wv0[k + 3];
      pacc1[r] += s4.x * wv1[k] + s4.y * wv1[k + 1] + s4.z * wv1[k + 2] + s4.w * wv1[k + 3];
    }
  }
#pragma unroll
  for (int r = 0; r < 8; ++r) {
    int row = row0 + r;
    if (row < NN) {
      Pout[(((size_t)b * 2 + 0) * NN + row) * 64 + lane] = pacc0[r];
      Pout[(((size_t)b * 2 + 1) * NN + row) * 64 + lane] = pacc1[r];
    }
  }
}

// ---------------- K_final: max over 13 rowgroup partials + classifier ----------------
__global__ __launch_bounds__(64) void k_final(
    const float* __restrict__ pooled, const float* __restrict__ fw,
    const float* __restrict__ fb, float* __restrict__ out) {
  int b = blockIdx.x;
  int t = threadIdx.x;
  __shared__ float sp[FF];
  float m = -3.402823466e38f;
  const float* pb = pooled + (size_t)b * 16 * 64;
#pragma unroll
  for (int rg = 0; rg < 13; ++rg) m = fmaxf(m, pb[rg * 64 + t]);
  sp[t] = m;
  __syncthreads();
  if (t < 16) {
    float acc = fb[t];
#pragma unroll
    for (int f = 0; f < FF; ++f) acc += sp[f] * fw[f * 16 + t];
    out[b * 16 + t] = acc;
  }
}

extern "C" void kernel_launch(void* const* d_in, const int* in_sizes, int n_in,
                              void* d_out, int out_size, void* d_ws, size_t ws_size,
                              hipStream_t stream) {
  const float* x    = (const float*)d_in[0];
  const float* A    = (const float*)d_in[1];
  const float* mask = (const float*)d_in[2];
  const float* ew1  = (const float*)d_in[3];
  const float* eb1  = (const float*)d_in[4];
  const float* ew2  = (const float*)d_in[5];
  const float* eb2  = (const float*)d_in[6];
  const float* gw0  = (const float*)d_in[7];
  const float* gb0  = (const float*)d_in[8];
  const float* gw1  = (const float*)d_in[9];
  const float* gb1  = (const float*)d_in[10];
  const float* gw2  = (const float*)d_in[11];
  const float* gb2  = (const float*)d_in[12];
  const float* fw   = (const float*)d_in[13];
  const float* fb   = (const float*)d_in[14];
  float* out = (float*)d_out;
  float* ws = (float*)d_ws;

  const int B = 128;
  float* hi  = ws;                   // 409600
  float* hj  = hi + 409600;          // 409600
  float* Ah1 = hj + 409600;          // 1280000
  float* d0  = Ah1 + 1280000;        // 12800
  float* d1  = d0 + 12800;           // 12800
  float* Pa  = d1 + 12800;           // 1638400  [B][2][100][64]
  float* Pb  = Pa + 1638400;         // 1638400
  float* pooled = Pb + 1638400;      // 128*16*64 = 131072

  k_hidden<<<B * NN, 64, 0, stream>>>(x, A, ew1, eb1, hi, hj, d0);
  k_edge<<<B * 10, 256, 0, stream>>>(hi, hj, ew2, eb2, mask, Ah1, d1);
  k_pre2<<<512, 256, 0, stream>>>(x, gw0, Pa);
  k_layer<0><<<512, 256, 0, stream>>>(A, Ah1, d0, d1, mask, Pa, gb0, gw1, Pb);
  k_layer<0><<<512, 256, 0, stream>>>(A, Ah1, d0, d1, mask, Pb, gb1, gw2, Pa);
  k_layer<1><<<512, 256, 0, stream>>>(A, Ah1, d0, d1, mask, Pa, gb2, gw2, pooled);
  k_final<<<B, 64, 0, stream>>>(pooled, fw, fb, out);
}

// Round 4
// 145.060 us; speedup vs baseline: 1.7477x; 1.7477x over previous
//
#include <hip/hip_runtime.h>

#define NN 100
#define CC 32
#define HEE 32
#define FF 64
#define TILE 10

// ---------------- K1: hi = x@ew1[:C]+eb1, hj = x@ew1[C:], d0 ----------------
__global__ __launch_bounds__(64) void k_hidden(
    const float* __restrict__ x, const float* __restrict__ A,
    const float* __restrict__ ew1, const float* __restrict__ eb1,
    float* __restrict__ hi, float* __restrict__ hj, float* __restrict__ d0) {
  int bn = blockIdx.x;
  int t = threadIdx.x;
  __shared__ float xr[CC];
  if (t < CC) xr[t] = x[bn * CC + t];

  const float* arow = A + (size_t)bn * NN;
  float s = 0.f;
  for (int j = t; j < NN; j += 64) s += arow[j];
#pragma unroll
  for (int off = 32; off > 0; off >>= 1) s += __shfl_down(s, off);
  if (t == 0) d0[bn] = 1.0f / sqrtf(s + 1.0f + 1e-5f);

  __syncthreads();
  int k = t & 31;
  const float* w = ew1 + (t < 32 ? 0 : CC * HEE) + k;
  float acc = (t < 32) ? eb1[k] : 0.f;
#pragma unroll
  for (int c = 0; c < CC; ++c) acc += xr[c] * w[c * HEE];
  if (t < 32) hi[bn * HEE + k] = acc;
  else        hj[bn * HEE + k] = acc;
}

// ---------------- K2: Ahat1 = A_pred + I, d1 ----------------
__global__ __launch_bounds__(256) void k_edge(
    const float* __restrict__ hi, const float* __restrict__ hj,
    const float* __restrict__ ew2, const float* __restrict__ eb2,
    const float* __restrict__ mask,
    float* __restrict__ Ahat1, float* __restrict__ d1) {
  __shared__ __align__(16) float shi[NN * HEE];
  __shared__ __align__(16) float shj[NN * HEE];
  __shared__ __align__(16) float sw2[HEE];
  __shared__ float sm[NN];
  __shared__ float sA[TILE][NN];
  int t = threadIdx.x;
  int b = blockIdx.x / 10;
  int i0 = (blockIdx.x % 10) * TILE;

  const float4* hi4 = (const float4*)(hi + (size_t)b * NN * HEE);
  const float4* hj4 = (const float4*)(hj + (size_t)b * NN * HEE);
  float4* shi4 = (float4*)shi;
  float4* shj4 = (float4*)shj;
  for (int v = t; v < NN * 8; v += 256) {
    int j = v >> 3, k4 = v & 7;
    int sw = (j << 3) | (k4 ^ (j & 7));
    shi4[sw] = hi4[v];
    shj4[sw] = hj4[v];
  }
  if (t < HEE) sw2[t] = ew2[t];
  if (t < NN) sm[t] = mask[b * NN + t];
  __syncthreads();

  float e2 = eb2[0];
  float4* sw24 = (float4*)sw2;
  for (int p = t; p < TILE * NN; p += 256) {
    int r = p / NN, j = p % NN, i = i0 + r;
    float val;
    if (j == i) {
      val = 1.0f;
    } else {
      float a1 = 0.f, a2 = 0.f;
#pragma unroll
      for (int k4 = 0; k4 < 8; ++k4) {
        float4 hii = shi4[(i << 3) | (k4 ^ (i & 7))];
        float4 hji = shj4[(i << 3) | (k4 ^ (i & 7))];
        float4 hij = shi4[(j << 3) | (k4 ^ (j & 7))];
        float4 hjj = shj4[(j << 3) | (k4 ^ (j & 7))];
        float4 w4 = sw24[k4];
        a1 += fmaxf(hii.x + hjj.x, 0.f) * w4.x;
        a2 += fmaxf(hij.x + hji.x, 0.f) * w4.x;
        a1 += fmaxf(hii.y + hjj.y, 0.f) * w4.y;
        a2 += fmaxf(hij.y + hji.y, 0.f) * w4.y;
        a1 += fmaxf(hii.z + hjj.z, 0.f) * w4.z;
        a2 += fmaxf(hij.z + hji.z, 0.f) * w4.z;
        a1 += fmaxf(hii.w + hjj.w, 0.f) * w4.w;
        a2 += fmaxf(hij.w + hji.w, 0.f) * w4.w;
      }
      val = expf(0.5f * (a1 + a2) + e2) * sm[i] * sm[j];
    }
    sA[r][j] = val;
    Ahat1[((size_t)b * NN + i) * NN + j] = val;
  }
  __syncthreads();
  if (t < TILE) {
    float s = 0.f;
    for (int j = 0; j < NN; ++j) s += sA[t][j];
    d1[b * NN + i0 + t] = 1.0f / sqrtf(s + 1e-5f);
  }
}

// ---------------- K_pre: P[b][rel][i][f] = sum_c x[b][i][c] * gw0[rel*32+c][f] ----------------
__global__ __launch_bounds__(256, 2) void k_pre2(
    const float* __restrict__ x, const float* __restrict__ gw0,
    float* __restrict__ P) {
  int t = threadIdx.x;
  int b = blockIdx.x & 127;
  int q = blockIdx.x >> 7;
  int wid = __builtin_amdgcn_readfirstlane(t >> 6);
  int lane = t & 63;
  int rg = wid * 4 + q;
  int row0 = rg * 8;
  if (row0 >= NN) return;

  int rowc[8];
#pragma unroll
  for (int r = 0; r < 8; ++r) rowc[r] = min(row0 + r, NN - 1);

  float acc0[8], acc1[8];
#pragma unroll
  for (int r = 0; r < 8; ++r) { acc0[r] = 0.f; acc1[r] = 0.f; }

  for (int c4 = 0; c4 < CC / 4; ++c4) {
    int c = c4 * 4;
    float w00 = gw0[(size_t)c * 64 + lane];
    float w01 = gw0[(size_t)(c + 1) * 64 + lane];
    float w02 = gw0[(size_t)(c + 2) * 64 + lane];
    float w03 = gw0[(size_t)(c + 3) * 64 + lane];
    float w10 = gw0[(size_t)(CC + c) * 64 + lane];
    float w11 = gw0[(size_t)(CC + c + 1) * 64 + lane];
    float w12 = gw0[(size_t)(CC + c + 2) * 64 + lane];
    float w13 = gw0[(size_t)(CC + c + 3) * 64 + lane];
#pragma unroll
    for (int r = 0; r < 8; ++r) {
      float4 a4 = *(const float4*)(x + ((size_t)b * NN + rowc[r]) * CC + c);
      acc0[r] += a4.x * w00 + a4.y * w01 + a4.z * w02 + a4.w * w03;
      acc1[r] += a4.x * w10 + a4.y * w11 + a4.z * w12 + a4.w * w13;
    }
  }
#pragma unroll
  for (int r = 0; r < 8; ++r) {
    int row = row0 + r;
    if (row < NN) {
      P[(((size_t)b * 2 + 0) * NN + row) * 64 + lane] = acc0[r];
      P[(((size_t)b * 2 + 1) * NN + row) * 64 + lane] = acc1[r];
    }
  }
}

// ---------------- K_layer ----------------
// out[i][f] = relu((d0_i*(sum_j A_ij*Pd0[j][f] + Pd0[i][f]) + d1_i*sum_j Ah1_ij*Pd1[j][f] + b[f])*m_i)
// Pd_rel[j][f] = d_rel[j]*P[b][rel][j][f], staged UNtransposed in LDS (lane=f -> conflict-free b32).
// A/Ah1 rows stream through SGPRs (wave-uniform addresses).
// Non-LAST: P_next[rel][i][f] = sum_k out[i][k]*Wn[rel*64+k][f], Wn read from global (L1).
template <int LAST>
__global__ __launch_bounds__(512, 2) void k_layer(
    const float* __restrict__ A, const float* __restrict__ Ah1,
    const float* __restrict__ d0, const float* __restrict__ d1,
    const float* __restrict__ mask, const float* __restrict__ Pin,
    const float* __restrict__ bias, const float* __restrict__ Wn,
    float* __restrict__ Pout) {
  __shared__ __align__(16) float sP[2][NN][64];   // scaled by d[j]
  __shared__ __align__(16) float srow[8][8][64];  // per-wave out rows
  int t = threadIdx.x;
  int b = blockIdx.x >> 1;
  int q = blockIdx.x & 1;

  // stage sP[rel][j][f] = P[b][rel][j][f] * d_rel[j]  (straight copy, no transpose)
  {
    const float4* P4 = (const float4*)(Pin + (size_t)b * 12800);
    float4* sP4 = (float4*)&sP[0][0][0];
    const float* d0b = d0 + b * NN;
    const float* d1b = d1 + b * NN;
    for (int v = t; v < 3200; v += 512) {
      int rel = (v >= 1600) ? 1 : 0;
      int rem = v - rel * 1600;
      int j = rem >> 4;
      float dv = rel ? d1b[j] : d0b[j];
      float4 p = P4[v];
      p.x *= dv; p.y *= dv; p.z *= dv; p.w *= dv;
      sP4[v] = p;
    }
  }
  __syncthreads();

  int wid = __builtin_amdgcn_readfirstlane(t >> 6);
  int lane = t & 63;
  int rg = q * 8 + wid;
  if (rg >= 13) return;  // no barriers below; srow is wave-private
  int row0 = rg * 8;

  int rowc[8];
#pragma unroll
  for (int r = 0; r < 8; ++r) rowc[r] = min(row0 + r, NN - 1);

  float acc0[8], acc1[8];
#pragma unroll
  for (int r = 0; r < 8; ++r) { acc0[r] = 0.f; acc1[r] = 0.f; }

  const float* A_b = A + (size_t)b * NN * NN;
  const float* Ah_b = Ah1 + (size_t)b * NN * NN;

#pragma unroll 1
  for (int j4 = 0; j4 < NN / 4; ++j4) {
    int j = j4 * 4;
    float p00 = sP[0][j][lane], p01 = sP[0][j + 1][lane];
    float p02 = sP[0][j + 2][lane], p03 = sP[0][j + 3][lane];
    float p10 = sP[1][j][lane], p11 = sP[1][j + 1][lane];
    float p12 = sP[1][j + 2][lane], p13 = sP[1][j + 3][lane];
#pragma unroll
    for (int r = 0; r < 8; ++r) {
      float4 a0 = *(const float4*)(A_b + (size_t)rowc[r] * NN + j);
      acc0[r] += a0.x * p00 + a0.y * p01 + a0.z * p02 + a0.w * p03;
      float4 a1 = *(const float4*)(Ah_b + (size_t)rowc[r] * NN + j);
      acc1[r] += a1.x * p10 + a1.y * p11 + a1.z * p12 + a1.w * p13;
    }
  }

  float vb = bias[lane];
  const float* d0b = d0 + b * NN;
  const float* d1b = d1 + b * NN;
  const float* mb = mask + b * NN;
  float outv[8];
#pragma unroll
  for (int r = 0; r < 8; ++r) {
    float d0r = d0b[rowc[r]];
    float d1r = d1b[rowc[r]];
    float mr = mb[rowc[r]];
    float pdiag = sP[0][rowc[r]][lane];  // Pd0[row][lane]  (+I term of rel0)
    float v = (acc0[r] + pdiag) * d0r + acc1[r] * d1r;
    v = (v + vb) * mr;
    outv[r] = fmaxf(v, 0.f);
  }

  if (LAST) {
    float mx = outv[0];
#pragma unroll
    for (int r = 1; r < 8; ++r) mx = fmaxf(mx, outv[r]);
    Pout[((size_t)b * 16 + rg) * 64 + lane] = mx;
    return;
  }

  // phase 2: P_next = out @ Wn   (srow wave-private, no barrier)
#pragma unroll
  for (int r = 0; r < 8; ++r) srow[wid][r][lane] = outv[r];

  float pacc0[8], pacc1[8];
#pragma unroll
  for (int r = 0; r < 8; ++r) { pacc0[r] = 0.f; pacc1[r] = 0.f; }

#pragma unroll 1
  for (int k4 = 0; k4 < 16; ++k4) {
    int k = k4 * 4;
    float w00 = Wn[(size_t)k * 64 + lane];
    float w01 = Wn[(size_t)(k + 1) * 64 + lane];
    float w02 = Wn[(size_t)(k + 2) * 64 + lane];
    float w03 = Wn[(size_t)(k + 3) * 64 + lane];
    float w10 = Wn[(size_t)(64 + k) * 64 + lane];
    float w11 = Wn[(size_t)(64 + k + 1) * 64 + lane];
    float w12 = Wn[(size_t)(64 + k + 2) * 64 + lane];
    float w13 = Wn[(size_t)(64 + k + 3) * 64 + lane];
#pragma unroll
    for (int r = 0; r < 8; ++r) {
      float4 s4 = *(const float4*)&srow[wid][r][k];  // broadcast read
      pacc0[r] += s4.x * w00 + s4.y * w01 + s4.z * w02 + s4.w * w03;
      pacc1[r] += s4.x * w10 + s4.y * w11 + s4.z * w12 + s4.w * w13;
    }
  }
#pragma unroll
  for (int r = 0; r < 8; ++r) {
    int row = row0 + r;
    if (row < NN) {
      Pout[(((size_t)b * 2 + 0) * NN + row) * 64 + lane] = pacc0[r];
      Pout[(((size_t)b * 2 + 1) * NN + row) * 64 + lane] = pacc1[r];
    }
  }
}

// ---------------- K_final: max over 13 rowgroup partials + classifier ----------------
__global__ __launch_bounds__(64) void k_final(
    const float* __restrict__ pooled, const float* __restrict__ fw,
    const float* __restrict__ fb, float* __restrict__ out) {
  int b = blockIdx.x;
  int t = threadIdx.x;
  __shared__ float sp[FF];
  float m = -3.402823466e38f;
  const float* pb = pooled + (size_t)b * 16 * 64;
#pragma unroll
  for (int rg = 0; rg < 13; ++rg) m = fmaxf(m, pb[rg * 64 + t]);
  sp[t] = m;
  __syncthreads();
  if (t < 16) {
    float acc = fb[t];
#pragma unroll
    for (int f = 0; f < FF; ++f) acc += sp[f] * fw[f * 16 + t];
    out[b * 16 + t] = acc;
  }
}

extern "C" void kernel_launch(void* const* d_in, const int* in_sizes, int n_in,
                              void* d_out, int out_size, void* d_ws, size_t ws_size,
                              hipStream_t stream) {
  const float* x    = (const float*)d_in[0];
  const float* A    = (const float*)d_in[1];
  const float* mask = (const float*)d_in[2];
  const float* ew1  = (const float*)d_in[3];
  const float* eb1  = (const float*)d_in[4];
  const float* ew2  = (const float*)d_in[5];
  const float* eb2  = (const float*)d_in[6];
  const float* gw0  = (const float*)d_in[7];
  const float* gb0  = (const float*)d_in[8];
  const float* gw1  = (const float*)d_in[9];
  const float* gb1  = (const float*)d_in[10];
  const float* gw2  = (const float*)d_in[11];
  const float* gb2  = (const float*)d_in[12];
  const float* fw   = (const float*)d_in[13];
  const float* fb   = (const float*)d_in[14];
  float* out = (float*)d_out;
  float* ws = (float*)d_ws;

  const int B = 128;
  float* hi  = ws;                   // 409600
  float* hj  = hi + 409600;          // 409600
  float* Ah1 = hj + 409600;          // 1280000
  float* d0  = Ah1 + 1280000;        // 12800
  float* d1  = d0 + 12800;           // 12800
  float* Pa  = d1 + 12800;           // 1638400  [B][2][100][64]
  float* Pb  = Pa + 1638400;         // 1638400
  float* pooled = Pb + 1638400;      // 128*16*64 = 131072

  k_hidden<<<B * NN, 64, 0, stream>>>(x, A, ew1, eb1, hi, hj, d0);
  k_edge<<<B * 10, 256, 0, stream>>>(hi, hj, ew2, eb2, mask, Ah1, d1);
  k_pre2<<<512, 256, 0, stream>>>(x, gw0, Pa);
  k_layer<0><<<B * 2, 512, 0, stream>>>(A, Ah1, d0, d1, mask, Pa, gb0, gw1, Pb);
  k_layer<0><<<B * 2, 512, 0, stream>>>(A, Ah1, d0, d1, mask, Pb, gb1, gw2, Pa);
  k_layer<1><<<B * 2, 512, 0, stream>>>(A, Ah1, d0, d1, mask, Pa, gb2, gw2, pooled);
  k_final<<<B, 64, 0, stream>>>(pooled, fw, fb, out);
}